// Round 3
// baseline (662.434 us; speedup 1.0000x reference)
//
#include <hip/hip_runtime.h>
#include <math.h>

#define DEV_INLINE __device__ __forceinline__

typedef __attribute__((ext_vector_type(8))) short short8v;
typedef __attribute__((ext_vector_type(4))) float float4v;

// fp32 -> bf16 round-to-nearest-even (finite data only)
DEV_INLINE unsigned short f2bf_rtn(float f) {
  unsigned u = __float_as_uint(f);
  u += 0x7FFFu + ((u >> 16) & 1u);
  return (unsigned short)(u >> 16);
}
DEV_INLINE float bf2f(unsigned short s) { return __uint_as_float(((unsigned)s) << 16); }

// LDS swizzle: row-major [row][32 shorts], k-oct (16B unit) XORed with (row>>1)&3.
// Verified round 1/2: SQ_LDS_BANK_CONFLICT == 0 with this mapping.
DEV_INLINE int soff(int row, int oct) { return row * 32 + ((oct ^ ((row >> 1) & 3)) << 3); }

// ---------------------------------------------------------------------------
// Pre-pass: all three weight matrices -> transposed bf16 hi/lo planes.
// ---------------------------------------------------------------------------
__global__ void conv_w_all(const float* __restrict__ W0, const float* __restrict__ W1,
                           const float* __restrict__ W2, short* __restrict__ w0h,
                           short* __restrict__ w0l, short* __restrict__ w1h,
                           short* __restrict__ w1l, short* __restrict__ w2h,
                           short* __restrict__ w2l) {
  const int S0 = 256 * 192, S1 = 192 * 192, S2 = 192 * 40;
  int idx = blockIdx.x * 256 + threadIdx.x;
  const float* W; short *Wh, *Wl; int K;
  if (idx < S0) { W = W0; Wh = w0h; Wl = w0l; K = 256; }
  else if (idx < S0 + S1) { idx -= S0; W = W1; Wh = w1h; Wl = w1l; K = 192; }
  else if (idx < S0 + S1 + S2) { idx -= S0 + S1; W = W2; Wh = w2h; Wl = w2l; K = 192; }
  else return;
  int n = idx / K, k = idx - n * K;
  int N = (W == W0 || W == W1) ? 192 : 40;
  float w = W[(size_t)k * N + n];
  unsigned short h = f2bf_rtn(w);
  Wh[idx] = (short)h;
  Wl[idx] = (short)f2bf_rtn(w - bf2f(h));
}

// ---------------------------------------------------------------------------
// Pre-pass: CSR offsets from all three sorted dst arrays.
// ---------------------------------------------------------------------------
__global__ void csr_all(const int* __restrict__ d0, const int* __restrict__ d1,
                        const int* __restrict__ d2, int* __restrict__ o0,
                        int* __restrict__ o1, int* __restrict__ o2,
                        int E0, int E1, int E2, int n1, int n2, int n3) {
  int i = blockIdx.x * 256 + threadIdx.x;
  const int* dst; int* off; int E, nd;
  if (i < E0) { dst = d0; off = o0; E = E0; nd = n1; }
  else if (i < E0 + E1) { i -= E0; dst = d1; off = o1; E = E1; nd = n2; }
  else if (i < E0 + E1 + E2) { i -= E0 + E1; dst = d2; off = o2; E = E2; nd = n3; }
  else return;
  int d = dst[i];
  int p = (i == 0) ? -1 : dst[i - 1];
  for (int q = p + 1; q <= d; ++q) off[q] = i;
  if (i == E - 1)
    for (int q = d + 1; q <= nd; ++q) off[q] = E;
}

// ---------------------------------------------------------------------------
// Full-width MFMA GEMM (bf16 3-term hi/lo split, fp32-accurate) with fused
// el/er epilogue.  BM=128, BN=NT*16 (full output width), BK=32, 256 threads.
//
// Round-3 structure (de-serialize the pipes):
//  * A NEVER goes through LDS: each wave loads its own 16-row x 32-k slab
//    straight to registers (16 aligned 128B segments -> fully coalesced,
//    same HBM bytes) and converts fp32->bf16 hi/lo in-register.
//  * B double-buffered in LDS (48KB for NT=12 -> 3 blocks/CU), ONE barrier
//    per K-step at the END: stage B(k+1) into buf^1 has no dependency on
//    MFMA(k) reading buf, so LDS writes / global-load issue / A-convert
//    VALU all overlap the MFMA cluster inside each wave.
//  * Macros, not lambdas (round-1 post-mortem: capturing prefetch arrays
//    by reference demotes them to scratch; WRITE_SIZE is the sentinel).
// LDS XOR-swizzled (soff): bank conflicts measured 0.
// ---------------------------------------------------------------------------
#define ISSUE_B(k0)                                                           \
  {                                                                           \
    _Pragma("unroll")                                                         \
    for (int q = 0; q < BREP; ++q) {                                          \
      int n = sr + q * 64;                                                    \
      if (n < BN) {                                                           \
        if (n < N) {                                                          \
          pbh[q] = *(const short8v*)(Bth + (size_t)n * K + (k0) + oct * 8);   \
          pbl[q] = *(const short8v*)(Btl + (size_t)n * K + (k0) + oct * 8);   \
        } else {                                                              \
          _Pragma("unroll")                                                   \
          for (int j = 0; j < 8; ++j) { pbh[q][j] = 0; pbl[q][j] = 0; }       \
        }                                                                     \
      }                                                                       \
    }                                                                         \
  }

#define STAGE_B(buf)                                                          \
  {                                                                           \
    _Pragma("unroll")                                                         \
    for (int q = 0; q < BREP; ++q) {                                          \
      int n = sr + q * 64;                                                    \
      if (n < BN) {                                                           \
        *(short8v*)(Bs_h[buf] + soff(n, oct)) = pbh[q];                       \
        *(short8v*)(Bs_l[buf] + soff(n, oct)) = pbl[q];                       \
      }                                                                       \
    }                                                                         \
  }

template <int NT, int H>
__global__ __launch_bounds__(256) void gemm_fused(
    const float* __restrict__ A, const short* __restrict__ Bth,
    const short* __restrict__ Btl, const float* __restrict__ al,
    const float* __restrict__ ar, float* __restrict__ C,
    float* __restrict__ el, float* __restrict__ er,
    int M, int N, int K, int n_dst) {
  constexpr int BN = NT * 16;
  constexpr int BREP = (BN + 63) / 64;
  constexpr int TPH = NT / H;  // column tiles per head
  __shared__ short Bs_h[2][BN * 32], Bs_l[2][BN * 32];
  const int tid = threadIdx.x;
  const int w = tid >> 6, lane = tid & 63;
  const int quad = lane >> 4, l16 = lane & 15;
  const int m0 = blockIdx.x * 128;

  float4v acc[2][NT];
#pragma unroll
  for (int mt = 0; mt < 2; ++mt)
#pragma unroll
    for (int nt = 0; nt < NT; ++nt)
#pragma unroll
      for (int r = 0; r < 4; ++r) acc[mt][nt][r] = 0.f;

  const int sr = tid >> 2;        // B stage row 0..63
  const int oct = tid & 3;        // k-oct 0..3

  // B prefetch registers (static indexing only — see round-1 note)
  short8v pbh[BREP], pbl[BREP];

  const int nk = K >> 5;
  // ---- prologue: buf0 <- B(0); B(1) in flight ----
  ISSUE_B(0);
  STAGE_B(0);
  if (nk > 1) ISSUE_B(32);
  __syncthreads();

  for (int kt = 0; kt < nk; ++kt) {
    const int cur = kt & 1;
    const int k0 = kt << 5;
    // ---- A direct loads for THIS step (issue early; consumed after stage) ----
    float4 fA[2][2];
#pragma unroll
    for (int mt = 0; mt < 2; ++mt) {
      int row = m0 + w * 32 + mt * 16 + l16;
      if (row < M) {
        const float* ap = A + (size_t)row * K + k0 + quad * 8;
        fA[mt][0] = *(const float4*)ap;
        fA[mt][1] = *(const float4*)(ap + 4);
      } else {
        fA[mt][0] = make_float4(0.f, 0.f, 0.f, 0.f);
        fA[mt][1] = fA[mt][0];
      }
    }
    // ---- stage B(k+1) into the other buffer (no dependency on MFMA(k)) ----
    if (kt + 1 < nk) STAGE_B(cur ^ 1);
    // ---- issue B(k+2) global loads ----
    if (kt + 2 < nk) ISSUE_B((kt + 2) << 5);
    // ---- convert A in-register ----
    short8v afh[2], afl[2];
#pragma unroll
    for (int mt = 0; mt < 2; ++mt) {
      float vs[8] = {fA[mt][0].x, fA[mt][0].y, fA[mt][0].z, fA[mt][0].w,
                     fA[mt][1].x, fA[mt][1].y, fA[mt][1].z, fA[mt][1].w};
#pragma unroll
      for (int j = 0; j < 8; ++j) {
        unsigned short hh = f2bf_rtn(vs[j]);
        afh[mt][j] = (short)hh;
        afl[mt][j] = (short)f2bf_rtn(vs[j] - bf2f(hh));
      }
    }
    // ---- B fragments from buf[cur] + MFMA ----
#pragma unroll
    for (int nt = 0; nt < NT; ++nt) {
      int col = nt * 16 + l16;
      short8v bfh = *(const short8v*)(Bs_h[cur] + soff(col, quad));
      short8v bfl = *(const short8v*)(Bs_l[cur] + soff(col, quad));
#pragma unroll
      for (int mt = 0; mt < 2; ++mt) {
        acc[mt][nt] = __builtin_amdgcn_mfma_f32_16x16x32_bf16(afh[mt], bfh, acc[mt][nt], 0, 0, 0);
        acc[mt][nt] = __builtin_amdgcn_mfma_f32_16x16x32_bf16(afh[mt], bfl, acc[mt][nt], 0, 0, 0);
        acc[mt][nt] = __builtin_amdgcn_mfma_f32_16x16x32_bf16(afl[mt], bfh, acc[mt][nt], 0, 0, 0);
      }
    }
    // ---- single barrier per K-step ----
    if (kt + 1 < nk) __syncthreads();
  }

  // ---- epilogue: C store + fused el/er ----
  float av[NT], rv[NT];
#pragma unroll
  for (int nt = 0; nt < NT; ++nt) {
    int col = nt * 16 + l16;
    av[nt] = (col < N) ? al[col] : 0.f;
    rv[nt] = (col < N) ? ar[col] : 0.f;
  }
#pragma unroll
  for (int mt = 0; mt < 2; ++mt)
#pragma unroll
    for (int r = 0; r < 4; ++r) {
      int gm = m0 + w * 32 + mt * 16 + quad * 4 + r;
      if (gm >= M) continue;
      float pl[H], pr[H];
#pragma unroll
      for (int h = 0; h < H; ++h) { pl[h] = 0.f; pr[h] = 0.f; }
#pragma unroll
      for (int nt = 0; nt < NT; ++nt) {
        int h = nt / TPH;
        pl[h] = fmaf(acc[mt][nt][r], av[nt], pl[h]);
        pr[h] = fmaf(acc[mt][nt][r], rv[nt], pr[h]);
      }
#pragma unroll
      for (int h = 0; h < H; ++h) {
#pragma unroll
        for (int o = 8; o >= 1; o >>= 1) {
          pl[h] += __shfl_xor(pl[h], o, 16);
          pr[h] += __shfl_xor(pr[h], o, 16);
        }
      }
      if (l16 == 0) {
#pragma unroll
        for (int h = 0; h < H; ++h) {
          el[gm * H + h] = pl[h];
          if (gm < n_dst) er[gm * H + h] = pr[h];
        }
      }
#pragma unroll
      for (int nt = 0; nt < NT; ++nt) {
        int col = nt * 16 + l16;
        if (col < N) C[(size_t)gm * N + col] = acc[mt][nt][r];
      }
    }
}

// ---------------------------------------------------------------------------
// Aggregation v2: 16-lane group per dst node (16 nodes/block), CSR ranges.
// Max-free softmax (|e| small -> exp safe; alpha mathematically identical).
// Per 16-edge chunk: phase 1 computes w=exp(lrelu(el+er)) edge-parallel into
// LDS; phase 2 gathers h rows with all lanes active + 1-deep prefetch.
// ---------------------------------------------------------------------------
template <int H, int D, bool RELU>
__global__ __launch_bounds__(256) void agg2_kernel(
    const float* __restrict__ hsrc, const float* __restrict__ el,
    const float* __restrict__ er, const int* __restrict__ src,
    const int* __restrict__ off, float* __restrict__ out, int n_dst) {
  constexpr int F = H * D;
  constexpr int NP = (F + 63) / 64;  // float4 passes per lane
  __shared__ float wbuf[16][16][H];
  __shared__ int sbuf[16][16];
  const int g = threadIdx.x >> 4, l = threadIdx.x & 15;
  const int d = blockIdx.x * 16 + g;
  if (d >= n_dst) return;
  const int lo = off[d], hi = off[d + 1];

  if (hi <= lo) {
#pragma unroll
    for (int p = 0; p < NP; ++p) {
      int c4 = (p * 16 + l) * 4;
      if (c4 < F) *(float4*)(out + (size_t)d * F + c4) = make_float4(0.f, 0.f, 0.f, 0.f);
    }
    return;
  }

  float erv[H], s_part[H];
#pragma unroll
  for (int h = 0; h < H; ++h) {
    erv[h] = er[d * H + h];
    s_part[h] = 0.f;
  }
  float4 acc[NP];
#pragma unroll
  for (int p = 0; p < NP; ++p) acc[p] = make_float4(0.f, 0.f, 0.f, 0.f);

  for (int base = lo; base < hi; base += 16) {
    const int i = base + l;
    const bool valid = i < hi;
    const int sid = valid ? src[i] : 0;
#pragma unroll
    for (int h = 0; h < H; ++h) {
      float e = 0.f;
      if (valid) {
        e = el[sid * H + h] + erv[h];
        e = e > 0.f ? e : 0.2f * e;  // leaky_relu 0.2
        e = __expf(e);
      }
      s_part[h] += e;
      wbuf[g][l][h] = e;
    }
    sbuf[g][l] = sid;  // same wave: no barrier needed

    const int cnt = min(16, hi - base);
    // prefetch edge 0
    int sj = sbuf[g][0];
    float4 hv[NP], hn[NP];
#pragma unroll
    for (int p = 0; p < NP; ++p) {
      int c4 = (p * 16 + l) * 4;
      hv[p] = (c4 < F) ? *(const float4*)(hsrc + (size_t)sj * F + c4)
                       : make_float4(0.f, 0.f, 0.f, 0.f);
    }
    for (int ei = 0; ei < cnt; ++ei) {
      if (ei + 1 < cnt) {
        int sj2 = sbuf[g][ei + 1];
#pragma unroll
        for (int p = 0; p < NP; ++p) {
          int c4 = (p * 16 + l) * 4;
          hn[p] = (c4 < F) ? *(const float4*)(hsrc + (size_t)sj2 * F + c4)
                           : make_float4(0.f, 0.f, 0.f, 0.f);
        }
      }
#pragma unroll
      for (int p = 0; p < NP; ++p) {
        int c4 = (p * 16 + l) * 4;
        float wc = wbuf[g][ei][c4 / D];
        acc[p].x = fmaf(wc, hv[p].x, acc[p].x);
        acc[p].y = fmaf(wc, hv[p].y, acc[p].y);
        acc[p].z = fmaf(wc, hv[p].z, acc[p].z);
        acc[p].w = fmaf(wc, hv[p].w, acc[p].w);
      }
#pragma unroll
      for (int p = 0; p < NP; ++p) hv[p] = hn[p];
    }
  }

#pragma unroll
  for (int h = 0; h < H; ++h)
#pragma unroll
    for (int o = 8; o >= 1; o >>= 1) s_part[h] += __shfl_xor(s_part[h], o, 16);

#pragma unroll
  for (int p = 0; p < NP; ++p) {
    int c4 = (p * 16 + l) * 4;
    if (c4 < F) {
      float inv = 1.f / s_part[c4 / D];
      float4 o;
      o.x = acc[p].x * inv; o.y = acc[p].y * inv;
      o.z = acc[p].z * inv; o.w = acc[p].w * inv;
      if (RELU) {
        o.x = fmaxf(o.x, 0.f); o.y = fmaxf(o.y, 0.f);
        o.z = fmaxf(o.z, 0.f); o.w = fmaxf(o.w, 0.f);
      }
      *(float4*)(out + (size_t)d * F + c4) = o;
    }
  }
}

// ---------------------------------------------------------------------------
extern "C" void kernel_launch(void* const* d_in, const int* in_sizes, int n_in,
                              void* d_out, int out_size, void* d_ws, size_t ws_size,
                              hipStream_t stream) {
  const float* x   = (const float*)d_in[0];
  const int* src0  = (const int*)d_in[1];
  const int* dst0  = (const int*)d_in[2];
  const int* src1  = (const int*)d_in[3];
  const int* dst1  = (const int*)d_in[4];
  const int* src2  = (const int*)d_in[5];
  const int* dst2  = (const int*)d_in[6];
  const float* W0  = (const float*)d_in[7];
  const float* al0 = (const float*)d_in[8];
  const float* ar0 = (const float*)d_in[9];
  const float* W1  = (const float*)d_in[10];
  const float* al1 = (const float*)d_in[11];
  const float* ar1 = (const float*)d_in[12];
  const float* W2  = (const float*)d_in[13];
  const float* al2 = (const float*)d_in[14];
  const float* ar2 = (const float*)d_in[15];

  const int N0 = 200000, N1 = 100000, N2 = 50000, N3 = 25000;
  const int E0 = in_sizes[1], E1 = in_sizes[3], E2 = in_sizes[5];
  const int Fin = 256, F = 192, C = 40;

  // ---- workspace layout ----
  float* ws     = (float*)d_ws;
  float* h_buf  = ws;                         // 200000*192
  float* o_buf  = h_buf + (size_t)N0 * F;     // 100000*192
  float* el_buf = o_buf + (size_t)N1 * F;     // 200000*3
  float* er_buf = el_buf + (size_t)N0 * 3;    // 100000*3
  short* w0h    = (short*)(er_buf + (size_t)N1 * 3);
  short* w0l    = w0h + 192 * 256;
  short* w1h    = w0l + 192 * 256;
  short* w1l    = w1h + 192 * 192;
  short* w2h    = w1l + 192 * 192;
  short* w2l    = w2h + 40 * 192;
  int*   off0   = (int*)(w2l + 40 * 192);
  int*   off1   = off0 + (N1 + 1);
  int*   off2   = off1 + (N2 + 1);

  dim3 blk(256);

  // ---- pre-passes ----
  const int WTOT = 256 * 192 + 192 * 192 + 192 * 40;
  conv_w_all<<<dim3((WTOT + 255) / 256), blk, 0, stream>>>(W0, W1, W2, w0h, w0l, w1h, w1l, w2h, w2l);
  const int ETOT = E0 + E1 + E2;
  csr_all<<<dim3((ETOT + 255) / 256), blk, 0, stream>>>(dst0, dst1, dst2, off0, off1, off2,
                                                        E0, E1, E2, N1, N2, N3);

  // ---- Layer 0 ----
  gemm_fused<12, 3><<<dim3((N0 + 127) / 128), blk, 0, stream>>>(
      x, w0h, w0l, al0, ar0, h_buf, el_buf, er_buf, N0, F, Fin, N1);
  agg2_kernel<3, 64, true><<<dim3((N1 + 15) / 16), blk, 0, stream>>>(
      h_buf, el_buf, er_buf, src0, off0, o_buf, N1);

  // ---- Layer 1 ----
  gemm_fused<12, 3><<<dim3((N1 + 127) / 128), blk, 0, stream>>>(
      o_buf, w1h, w1l, al1, ar1, h_buf, el_buf, er_buf, N1, F, F, N2);
  agg2_kernel<3, 64, true><<<dim3((N2 + 15) / 16), blk, 0, stream>>>(
      h_buf, el_buf, er_buf, src1, off1, o_buf, N2);

  // ---- Layer 2 (N=40, H=1, no relu) ----
  gemm_fused<3, 1><<<dim3((N2 + 127) / 128), blk, 0, stream>>>(
      o_buf, w2h, w2l, al2, ar2, h_buf, el_buf, er_buf, N2, C, F, N3);
  agg2_kernel<1, 40, false><<<dim3((N3 + 15) / 16), blk, 0, stream>>>(
      h_buf, el_buf, er_buf, src2, off2, (float*)d_out, N3);
}

// Round 4
// 637.793 us; speedup vs baseline: 1.0386x; 1.0386x over previous
//
#include <hip/hip_runtime.h>
#include <math.h>

#define DEV_INLINE __device__ __forceinline__

typedef __attribute__((ext_vector_type(8))) short short8v;
typedef __attribute__((ext_vector_type(4))) float float4v;

// fp32 -> bf16 round-to-nearest-even (finite data only)
DEV_INLINE unsigned short f2bf_rtn(float f) {
  unsigned u = __float_as_uint(f);
  u += 0x7FFFu + ((u >> 16) & 1u);
  return (unsigned short)(u >> 16);
}
DEV_INLINE float bf2f(unsigned short s) { return __uint_as_float(((unsigned)s) << 16); }

// LDS swizzle: row-major [row][32 shorts], k-oct (16B unit) XORed with (row>>1)&3.
// Verified rounds 1-3: SQ_LDS_BANK_CONFLICT == 0 with this mapping on the read side.
DEV_INLINE int soff(int row, int oct) { return row * 32 + ((oct ^ ((row >> 1) & 3)) << 3); }

// global -> LDS DMA, 16B per lane.  LDS dest is wave-uniform base + lane*16
// (hardware semantics); the swizzle is applied by INVERSE-swizzling the
// per-lane GLOBAL source address (rule: both-sides-or-neither).
DEV_INLINE void gload_lds16(const void* g, void* l) {
  __builtin_amdgcn_global_load_lds(
      (const __attribute__((address_space(1))) void*)g,
      (__attribute__((address_space(3))) void*)l, 16, 0, 0);
}

// ---------------------------------------------------------------------------
// Pre-pass: all three weight matrices -> transposed bf16 hi/lo planes.
// Layer-2 planes are PADDED to 48 rows (zeros for n in [40,48)) so the GEMM's
// unguarded B-DMA reads stay in-bounds and pad columns contribute exact 0.
// ---------------------------------------------------------------------------
__global__ void conv_w_all(const float* __restrict__ W0, const float* __restrict__ W1,
                           const float* __restrict__ W2, short* __restrict__ w0h,
                           short* __restrict__ w0l, short* __restrict__ w1h,
                           short* __restrict__ w1l, short* __restrict__ w2h,
                           short* __restrict__ w2l) {
  const int S0 = 256 * 192, S1 = 192 * 192, S2 = 192 * 48;
  int idx = blockIdx.x * 256 + threadIdx.x;
  const float* W; short *Wh, *Wl; int K;
  int which;
  if (idx < S0) { W = W0; Wh = w0h; Wl = w0l; K = 256; which = 0; }
  else if (idx < S0 + S1) { idx -= S0; W = W1; Wh = w1h; Wl = w1l; K = 192; which = 1; }
  else if (idx < S0 + S1 + S2) { idx -= S0 + S1; W = W2; Wh = w2h; Wl = w2l; K = 192; which = 2; }
  else return;
  int n = idx / K, k = idx - n * K;
  if (which == 2 && n >= 40) { Wh[idx] = 0; Wl[idx] = 0; return; }
  int N = (which == 2) ? 40 : 192;
  float w = W[(size_t)k * N + n];
  unsigned short h = f2bf_rtn(w);
  Wh[idx] = (short)h;
  Wl[idx] = (short)f2bf_rtn(w - bf2f(h));
}

// ---------------------------------------------------------------------------
// Pre-pass: CSR offsets from all three sorted dst arrays.
// ---------------------------------------------------------------------------
__global__ void csr_all(const int* __restrict__ d0, const int* __restrict__ d1,
                        const int* __restrict__ d2, int* __restrict__ o0,
                        int* __restrict__ o1, int* __restrict__ o2,
                        int E0, int E1, int E2, int n1, int n2, int n3) {
  int i = blockIdx.x * 256 + threadIdx.x;
  const int* dst; int* off; int E, nd;
  if (i < E0) { dst = d0; off = o0; E = E0; nd = n1; }
  else if (i < E0 + E1) { i -= E0; dst = d1; off = o1; E = E1; nd = n2; }
  else if (i < E0 + E1 + E2) { i -= E0 + E1; dst = d2; off = o2; E = E2; nd = n3; }
  else return;
  int d = dst[i];
  int p = (i == 0) ? -1 : dst[i - 1];
  for (int q = p + 1; q <= d; ++q) off[q] = i;
  if (i == E - 1)
    for (int q = d + 1; q <= nd; ++q) off[q] = E;
}

// ---------------------------------------------------------------------------
// Full-width MFMA GEMM (bf16 3-term hi/lo split, fp32-accurate) with fused
// el/er epilogue.  BM=128, BN=NT*16 (full output width), BK=32, 256 threads.
//
// Round-4 structure (raise occupancy — the rounds 0-3 invariant was
// 2 waves/SIMD from unified VGPR+AGPR ~212 [acc=96 AGPR + 116 VGPR]):
//  * A direct-to-register (transient), converted fp32->bf16 hi/lo in-reg.
//  * B staged via global_load_lds DMA (NO register transit, no ds_writes):
//    LDS dest linear per chunk (16 rows x 64B = 1KB = one wave-issue);
//    per-lane global source inverse-swizzled with the same involution the
//    soff() read applies -> LDS content identical to rounds 1-3.
//  * B double-buffered: 48KB LDS, one __syncthreads per K-step (its
//    implicit vmcnt(0) drain completes the next tile's DMA).
//  * __launch_bounds__(256,3): target 3 waves/SIMD (unified budget <=170).
//    Spill sentinel: WRITE_SIZE (round-1 lesson).
// ---------------------------------------------------------------------------
#define DMA_B(ktv, bufv)                                                      \
  {                                                                           \
    const int kb = (ktv) << 6; /* k0*2 bytes */                               \
    for (int c = w; c < NT; c += 4) {                                         \
      gload_lds16((const char*)Bth + (size_t)c * (K * 32) + voff + kb,        \
                  (short*)Bs_h[bufv] + c * 512);                              \
      gload_lds16((const char*)Btl + (size_t)c * (K * 32) + voff + kb,        \
                  (short*)Bs_l[bufv] + c * 512);                              \
    }                                                                         \
  }

template <int NT, int H>
__global__ __launch_bounds__(256, 3) void gemm_fused(
    const float* __restrict__ A, const short* __restrict__ Bth,
    const short* __restrict__ Btl, const float* __restrict__ al,
    const float* __restrict__ ar, float* __restrict__ C,
    float* __restrict__ el, float* __restrict__ er,
    int M, int N, int K, int n_dst) {
  constexpr int BN = NT * 16;
  constexpr int TPH = NT / H;  // column tiles per head
  __shared__ short Bs_h[2][BN * 32], Bs_l[2][BN * 32];
  const int tid = threadIdx.x;
  const int w = tid >> 6, lane = tid & 63;
  const int quad = lane >> 4, l16 = lane & 15;
  const int m0 = blockIdx.x * 128;

  // Per-lane inverse-swizzled source offset within a 16-row chunk:
  // row_in_chunk = lane>>2, oct_lds = lane&3, oct_src = oct_lds ^ ((row>>1)&3)
  //              = (lane&3) ^ ((lane>>3)&3)   [chunk base row is mult of 16].
  const int voff = (lane >> 2) * (K * 2) + ((((lane & 3) ^ ((lane >> 3) & 3))) << 4);

  float4v acc[2][NT];
#pragma unroll
  for (int mt = 0; mt < 2; ++mt)
#pragma unroll
    for (int nt = 0; nt < NT; ++nt)
#pragma unroll
      for (int r = 0; r < 4; ++r) acc[mt][nt][r] = 0.f;

  const int nk = K >> 5;
  // ---- prologue: DMA tile 0 into buf0 ----
  DMA_B(0, 0);
  __syncthreads();  // implicit vmcnt(0) drain completes the DMA

  for (int kt = 0; kt < nk; ++kt) {
    const int cur = kt & 1;
    // ---- A direct loads (issue first: longest latency) ----
    float4 xa[2][2];
#pragma unroll
    for (int mt = 0; mt < 2; ++mt) {
      int row = m0 + w * 32 + mt * 16 + l16;
      if (row < M) {
        const float* ap = A + (size_t)row * K + (kt << 5) + quad * 8;
        xa[mt][0] = *(const float4*)ap;
        xa[mt][1] = *(const float4*)(ap + 4);
      } else {
        xa[mt][0] = make_float4(0.f, 0.f, 0.f, 0.f);
        xa[mt][1] = xa[mt][0];
      }
    }
    // ---- DMA next B tile into the other buffer (no reg transit) ----
    if (kt + 1 < nk) DMA_B(kt + 1, cur ^ 1);
    // ---- convert A in-register ----
    short8v afh[2], afl[2];
#pragma unroll
    for (int mt = 0; mt < 2; ++mt) {
      float vs[8] = {xa[mt][0].x, xa[mt][0].y, xa[mt][0].z, xa[mt][0].w,
                     xa[mt][1].x, xa[mt][1].y, xa[mt][1].z, xa[mt][1].w};
#pragma unroll
      for (int j = 0; j < 8; ++j) {
        unsigned short hh = f2bf_rtn(vs[j]);
        afh[mt][j] = (short)hh;
        afl[mt][j] = (short)f2bf_rtn(vs[j] - bf2f(hh));
      }
    }
    // ---- B fragments from buf[cur] + MFMA ----
#pragma unroll
    for (int nt = 0; nt < NT; ++nt) {
      int col = nt * 16 + l16;
      short8v bfh = *(const short8v*)(Bs_h[cur] + soff(col, quad));
      short8v bfl = *(const short8v*)(Bs_l[cur] + soff(col, quad));
#pragma unroll
      for (int mt = 0; mt < 2; ++mt) {
        acc[mt][nt] = __builtin_amdgcn_mfma_f32_16x16x32_bf16(afh[mt], bfh, acc[mt][nt], 0, 0, 0);
        acc[mt][nt] = __builtin_amdgcn_mfma_f32_16x16x32_bf16(afh[mt], bfl, acc[mt][nt], 0, 0, 0);
        acc[mt][nt] = __builtin_amdgcn_mfma_f32_16x16x32_bf16(afl[mt], bfh, acc[mt][nt], 0, 0, 0);
      }
    }
    // ---- one barrier per K-step (drains next tile's DMA + read fence) ----
    if (kt + 1 < nk) __syncthreads();
  }

  // ---- epilogue: C store + fused el/er ----
  float av[NT], rv[NT];
#pragma unroll
  for (int nt = 0; nt < NT; ++nt) {
    int col = nt * 16 + l16;
    av[nt] = (col < N) ? al[col] : 0.f;
    rv[nt] = (col < N) ? ar[col] : 0.f;
  }
#pragma unroll
  for (int mt = 0; mt < 2; ++mt)
#pragma unroll
    for (int r = 0; r < 4; ++r) {
      int gm = m0 + w * 32 + mt * 16 + quad * 4 + r;
      if (gm >= M) continue;
      float pl[H], pr[H];
#pragma unroll
      for (int h = 0; h < H; ++h) { pl[h] = 0.f; pr[h] = 0.f; }
#pragma unroll
      for (int nt = 0; nt < NT; ++nt) {
        int h = nt / TPH;
        pl[h] = fmaf(acc[mt][nt][r], av[nt], pl[h]);
        pr[h] = fmaf(acc[mt][nt][r], rv[nt], pr[h]);
      }
#pragma unroll
      for (int h = 0; h < H; ++h) {
#pragma unroll
        for (int o = 8; o >= 1; o >>= 1) {
          pl[h] += __shfl_xor(pl[h], o, 16);
          pr[h] += __shfl_xor(pr[h], o, 16);
        }
      }
      if (l16 == 0) {
#pragma unroll
        for (int h = 0; h < H; ++h) {
          el[gm * H + h] = pl[h];
          if (gm < n_dst) er[gm * H + h] = pr[h];
        }
      }
#pragma unroll
      for (int nt = 0; nt < NT; ++nt) {
        int col = nt * 16 + l16;
        if (col < N) C[(size_t)gm * N + col] = acc[mt][nt][r];
      }
    }
}

// ---------------------------------------------------------------------------
// Aggregation v2: 16-lane group per dst node (16 nodes/block), CSR ranges.
// Max-free softmax (|e| small -> exp safe; alpha mathematically identical).
// Per 16-edge chunk: phase 1 computes w=exp(lrelu(el+er)) edge-parallel into
// LDS; phase 2 gathers h rows with all lanes active + 1-deep prefetch.
// ---------------------------------------------------------------------------
template <int H, int D, bool RELU>
__global__ __launch_bounds__(256) void agg2_kernel(
    const float* __restrict__ hsrc, const float* __restrict__ el,
    const float* __restrict__ er, const int* __restrict__ src,
    const int* __restrict__ off, float* __restrict__ out, int n_dst) {
  constexpr int F = H * D;
  constexpr int NP = (F + 63) / 64;  // float4 passes per lane
  __shared__ float wbuf[16][16][H];
  __shared__ int sbuf[16][16];
  const int g = threadIdx.x >> 4, l = threadIdx.x & 15;
  const int d = blockIdx.x * 16 + g;
  if (d >= n_dst) return;
  const int lo = off[d], hi = off[d + 1];

  if (hi <= lo) {
#pragma unroll
    for (int p = 0; p < NP; ++p) {
      int c4 = (p * 16 + l) * 4;
      if (c4 < F) *(float4*)(out + (size_t)d * F + c4) = make_float4(0.f, 0.f, 0.f, 0.f);
    }
    return;
  }

  float erv[H], s_part[H];
#pragma unroll
  for (int h = 0; h < H; ++h) {
    erv[h] = er[d * H + h];
    s_part[h] = 0.f;
  }
  float4 acc[NP];
#pragma unroll
  for (int p = 0; p < NP; ++p) acc[p] = make_float4(0.f, 0.f, 0.f, 0.f);

  for (int base = lo; base < hi; base += 16) {
    const int i = base + l;
    const bool valid = i < hi;
    const int sid = valid ? src[i] : 0;
#pragma unroll
    for (int h = 0; h < H; ++h) {
      float e = 0.f;
      if (valid) {
        e = el[sid * H + h] + erv[h];
        e = e > 0.f ? e : 0.2f * e;  // leaky_relu 0.2
        e = __expf(e);
      }
      s_part[h] += e;
      wbuf[g][l][h] = e;
    }
    sbuf[g][l] = sid;  // same wave: no barrier needed

    const int cnt = min(16, hi - base);
    // prefetch edge 0
    int sj = sbuf[g][0];
    float4 hv[NP], hn[NP];
#pragma unroll
    for (int p = 0; p < NP; ++p) {
      int c4 = (p * 16 + l) * 4;
      hv[p] = (c4 < F) ? *(const float4*)(hsrc + (size_t)sj * F + c4)
                       : make_float4(0.f, 0.f, 0.f, 0.f);
    }
    for (int ei = 0; ei < cnt; ++ei) {
      if (ei + 1 < cnt) {
        int sj2 = sbuf[g][ei + 1];
#pragma unroll
        for (int p = 0; p < NP; ++p) {
          int c4 = (p * 16 + l) * 4;
          hn[p] = (c4 < F) ? *(const float4*)(hsrc + (size_t)sj2 * F + c4)
                           : make_float4(0.f, 0.f, 0.f, 0.f);
        }
      }
#pragma unroll
      for (int p = 0; p < NP; ++p) {
        int c4 = (p * 16 + l) * 4;
        float wc = wbuf[g][ei][c4 / D];
        acc[p].x = fmaf(wc, hv[p].x, acc[p].x);
        acc[p].y = fmaf(wc, hv[p].y, acc[p].y);
        acc[p].z = fmaf(wc, hv[p].z, acc[p].z);
        acc[p].w = fmaf(wc, hv[p].w, acc[p].w);
      }
#pragma unroll
      for (int p = 0; p < NP; ++p) hv[p] = hn[p];
    }
  }

#pragma unroll
  for (int h = 0; h < H; ++h)
#pragma unroll
    for (int o = 8; o >= 1; o >>= 1) s_part[h] += __shfl_xor(s_part[h], o, 16);

#pragma unroll
  for (int p = 0; p < NP; ++p) {
    int c4 = (p * 16 + l) * 4;
    if (c4 < F) {
      float inv = 1.f / s_part[c4 / D];
      float4 o;
      o.x = acc[p].x * inv; o.y = acc[p].y * inv;
      o.z = acc[p].z * inv; o.w = acc[p].w * inv;
      if (RELU) {
        o.x = fmaxf(o.x, 0.f); o.y = fmaxf(o.y, 0.f);
        o.z = fmaxf(o.z, 0.f); o.w = fmaxf(o.w, 0.f);
      }
      *(float4*)(out + (size_t)d * F + c4) = o;
    }
  }
}

// ---------------------------------------------------------------------------
extern "C" void kernel_launch(void* const* d_in, const int* in_sizes, int n_in,
                              void* d_out, int out_size, void* d_ws, size_t ws_size,
                              hipStream_t stream) {
  const float* x   = (const float*)d_in[0];
  const int* src0  = (const int*)d_in[1];
  const int* dst0  = (const int*)d_in[2];
  const int* src1  = (const int*)d_in[3];
  const int* dst1  = (const int*)d_in[4];
  const int* src2  = (const int*)d_in[5];
  const int* dst2  = (const int*)d_in[6];
  const float* W0  = (const float*)d_in[7];
  const float* al0 = (const float*)d_in[8];
  const float* ar0 = (const float*)d_in[9];
  const float* W1  = (const float*)d_in[10];
  const float* al1 = (const float*)d_in[11];
  const float* ar1 = (const float*)d_in[12];
  const float* W2  = (const float*)d_in[13];
  const float* al2 = (const float*)d_in[14];
  const float* ar2 = (const float*)d_in[15];

  const int N0 = 200000, N1 = 100000, N2 = 50000, N3 = 25000;
  const int E0 = in_sizes[1], E1 = in_sizes[3], E2 = in_sizes[5];
  const int Fin = 256, F = 192, C = 40;

  // ---- workspace layout ----
  float* ws     = (float*)d_ws;
  float* h_buf  = ws;                         // 200000*192
  float* o_buf  = h_buf + (size_t)N0 * F;     // 100000*192
  float* el_buf = o_buf + (size_t)N1 * F;     // 200000*3
  float* er_buf = el_buf + (size_t)N0 * 3;    // 100000*3
  short* w0h    = (short*)(er_buf + (size_t)N1 * 3);
  short* w0l    = w0h + 192 * 256;
  short* w1h    = w0l + 192 * 256;
  short* w1l    = w1h + 192 * 192;
  short* w2h    = w1l + 192 * 192;
  short* w2l    = w2h + 48 * 192;   // layer-2 planes padded to 48 rows
  int*   off0   = (int*)(w2l + 48 * 192);
  int*   off1   = off0 + (N1 + 1);
  int*   off2   = off1 + (N2 + 1);

  dim3 blk(256);

  // ---- pre-passes ----
  const int WTOT = 256 * 192 + 192 * 192 + 192 * 48;
  conv_w_all<<<dim3((WTOT + 255) / 256), blk, 0, stream>>>(W0, W1, W2, w0h, w0l, w1h, w1l, w2h, w2l);
  const int ETOT = E0 + E1 + E2;
  csr_all<<<dim3((ETOT + 255) / 256), blk, 0, stream>>>(dst0, dst1, dst2, off0, off1, off2,
                                                        E0, E1, E2, N1, N2, N3);

  // ---- Layer 0 ----
  gemm_fused<12, 3><<<dim3((N0 + 127) / 128), blk, 0, stream>>>(
      x, w0h, w0l, al0, ar0, h_buf, el_buf, er_buf, N0, F, Fin, N1);
  agg2_kernel<3, 64, true><<<dim3((N1 + 15) / 16), blk, 0, stream>>>(
      h_buf, el_buf, er_buf, src0, off0, o_buf, N1);

  // ---- Layer 1 ----
  gemm_fused<12, 3><<<dim3((N1 + 127) / 128), blk, 0, stream>>>(
      o_buf, w1h, w1l, al1, ar1, h_buf, el_buf, er_buf, N1, F, F, N2);
  agg2_kernel<3, 64, true><<<dim3((N2 + 15) / 16), blk, 0, stream>>>(
      h_buf, el_buf, er_buf, src1, off1, o_buf, N2);

  // ---- Layer 2 (N=40, H=1, no relu) ----
  gemm_fused<3, 1><<<dim3((N2 + 127) / 128), blk, 0, stream>>>(
      o_buf, w2h, w2l, al2, ar2, h_buf, el_buf, er_buf, N2, C, F, N3);
  agg2_kernel<1, 40, false><<<dim3((N3 + 15) / 16), blk, 0, stream>>>(
      h_buf, el_buf, er_buf, src2, off2, (float*)d_out, N3);
}